// Round 15
// baseline (355.880 us; speedup 1.0000x reference)
//
#include <hip/hip_runtime.h>
#include <hip/hip_bf16.h>

typedef unsigned short ushort_t;
typedef __bf16 bf16x8 __attribute__((ext_vector_type(8)));
typedef float f32x4 __attribute__((ext_vector_type(4)));

typedef const void __attribute__((address_space(1)))* gas1_t;
typedef void __attribute__((address_space(3)))* las3_t;

#define L_SZ 2048
#define DI   2048
#define M_ROWS 4096
#define NC 64
#define TC 32

__device__ __forceinline__ float bf2f(ushort_t u){
  unsigned x = ((unsigned)u) << 16; float f; __builtin_memcpy(&f, &x, 4); return f;
}
__device__ __forceinline__ ushort_t f2bf(float f){
  __hip_bfloat16 h = __float2bfloat16(f);
  ushort_t u; __builtin_memcpy(&u, &h, 2); return u;
}
__device__ __forceinline__ float siluf(float x){ return x / (1.0f + __expf(-x)); }
__device__ __forceinline__ float softplusf(float x){
  return (x > 20.0f) ? x : log1pf(__expf(x));
}

// ---------------- fused prep: all weight transposes + x cast, ONE launch ----
// ids [0,10368): transposes; [10368,14464): x cast; [14464,14560): zero-fill
// W_bigT pad rows 2080..2175 (GEMM2 N padded to 33x64 = 2112).
__global__ __launch_bounds__(256) void k_prep(
    const float* __restrict__ W_in, const float* __restrict__ W_delta,
    const float* __restrict__ W_out, const float* __restrict__ W_B,
    const float* __restrict__ W_C, const float* __restrict__ x,
    ushort_t* __restrict__ W_inT, ushort_t* __restrict__ W_bigT,
    ushort_t* __restrict__ W_outT, ushort_t* __restrict__ xb)
{
  int t = blockIdx.x;
  if (t >= 14464){
    int r = 2080 + (t - 14464);
    uint4 z = make_uint4(0,0,0,0);
    *(uint4*)(W_bigT + (size_t)r * 2048 + threadIdx.x * 8) = z;
    return;
  }
  if (t >= 10368){
    size_t i = (size_t)(t - 10368) * 256 + threadIdx.x;
    float4 v = *(const float4*)(x + i * 4);
    ushort_t o[4] = { f2bf(v.x), f2bf(v.y), f2bf(v.z), f2bf(v.w) };
    *(uint2*)(xb + i * 4) = *(const uint2*)o;
    return;
  }
  const float* in; ushort_t* out; int R, C, tx, ty;
  if (t < 4096)      { in=W_in;    out=W_inT;  R=1024; C=4096; tx = t & 127; ty = t >> 7; }
  else if (t < 8192) { t -= 4096;  in=W_delta; out=W_bigT; R=2048; C=2048; tx = t & 63; ty = t >> 6; }
  else if (t < 10240){ t -= 8192;  in=W_out;   out=W_outT; R=2048; C=1024; tx = t & 31; ty = t >> 5; }
  else if (t < 10304){ t -= 10240; in=W_B;  out=W_bigT + (size_t)2048*2048; R=2048; C=16; tx=0; ty=t; }
  else               { t -= 10304; in=W_C;  out=W_bigT + (size_t)2064*2048; R=2048; C=16; tx=0; ty=t; }
  __shared__ ushort_t tile[32][33];
  int c0 = tx * 32, r0 = ty * 32;
  int xx = threadIdx.x & 31, yy = threadIdx.x >> 5;
  #pragma unroll
  for (int i = 0; i < 32; i += 8){
    int r = r0 + yy + i, c = c0 + xx;
    if (r < R && c < C) tile[yy + i][xx] = f2bf(in[(size_t)r * C + c]);
  }
  __syncthreads();
  #pragma unroll
  for (int i = 0; i < 32; i += 8){
    int c = c0 + yy + i, r = r0 + xx;
    if (r < R && c < C) out[(size_t)c * R + r] = tile[xx][yy + i];
  }
}

// ------------- 2-phase double-buffered GEMM: C = A[M,K] * Bt[N,K]^T --------
// CONVERGED core (R0-R11 search): BK=64, STAGE(buf^1,t+1) before compute, one
// __syncthreads per K-step; XOR-swizzled LDS via pre-swizzled source
// (conflicts=0); T1 XCD-chunked blockIdx swizzle (grid % 8 == 0).
// GEMM1 256x256/512thr/1 blk/CU; GEMM2/3 128x64/256thr/3 blk/CU.
// R15: GEMM2 as two M-halves again (diagnostic — re-expose post-R14 ranking).
// EPI: 0=fp32 store, 1=silu->bf16, 2=softplus(+bias)->bf16 + fused Bm/Cm
// at n in [2048,2080), discard n >= 2080 (padded N).
template<int BM, int BN, int TPB, int WR, int WC, int EPI, int MINW>
__global__ __launch_bounds__(TPB, MINW) void k_gemm2p(
    const ushort_t* __restrict__ A, int lda,
    const ushort_t* __restrict__ Bt, int ldb,
    void* __restrict__ Cout, int ldc,
    const float* __restrict__ bias,
    float* __restrict__ Bm, float* __restrict__ Cm, int K)
{
  constexpr int WM = BM / WR, WN = BN / WC;
  constexpr int MT = WM / 16, NT = WN / 16;
  constexpr int BUFSZ = (BM + BN) * 128;        // one K-step buffer (BK=64)
  constexpr int ACH = BM * 8;                   // 16B chunks of A per buffer
  constexpr int NISSUE = (BM + BN) * 8 / TPB;
  __shared__ __align__(16) char lds[2 * BUFSZ];
  const int tid  = threadIdx.x;
  const int wave = tid >> 6, lane = tid & 63;
  const int quad = lane >> 4, l16 = lane & 15;

  // T1: bijective XCD-chunked swizzle (gridDim.x*gridDim.y % 8 == 0)
  const int gx  = gridDim.x;
  const int nwg = gx * gridDim.y;
  const int bid = blockIdx.y * gx + blockIdx.x;
  const int cpx = nwg >> 3;
  const int wid = (bid & 7) * cpx + (bid >> 3);
  const int bx  = wid % gx, by = wid / gx;

  const int m_blk = by * BM, n_blk = bx * BN;
  const int wm = (wave / WC) * WM, wn = (wave % WC) * WN;

  f32x4 acc[MT][NT] = {};

  const ushort_t* gptr[NISSUE];
  char* lptr[NISSUE];
  #pragma unroll
  for (int i = 0; i < NISSUE; i++){
    int g = tid + i * TPB;
    if (g < ACH){
      int row = g >> 3, c = g & 7;
      gptr[i] = A + (size_t)(m_blk + row) * lda + ((c ^ (row & 7)) * 8);
    } else {
      int gb = g - ACH;
      int row = gb >> 3, c = gb & 7;
      gptr[i] = Bt + (size_t)(n_blk + row) * ldb + ((c ^ (row & 7)) * 8);
    }
    lptr[i] = lds + (size_t)g * 16;
  }

  const int xsw = (l16 & 7);
  const int NSTEP = K >> 6;

  #pragma unroll
  for (int i = 0; i < NISSUE; i++)
    __builtin_amdgcn_global_load_lds((gas1_t)(const void*)gptr[i], (las3_t)lptr[i], 16, 0, 0);
  __syncthreads();

  int cur = 0;
  for (int t = 0; t < NSTEP; ++t){
    if (t + 1 < NSTEP){
      const int nxt = (cur ^ 1) * BUFSZ;
      #pragma unroll
      for (int i = 0; i < NISSUE; i++)
        __builtin_amdgcn_global_load_lds((gas1_t)(const void*)(gptr[i] + (t + 1) * 64),
                                         (las3_t)(lptr[i] + nxt), 16, 0, 0);
    }
    const char* ldsA = lds + cur * BUFSZ;
    const char* ldsB = ldsA + BM * 128;
    #pragma unroll
    for (int s = 0; s < 2; s++){
      const int xa = ((s * 4 + quad) ^ xsw) * 16;
      bf16x8 af[MT], bfr[NT];
      #pragma unroll
      for (int i = 0; i < MT; i++)
        af[i]  = *(const bf16x8*)(ldsA + (wm + i * 16 + l16) * 128 + xa);
      #pragma unroll
      for (int i = 0; i < NT; i++)
        bfr[i] = *(const bf16x8*)(ldsB + (wn + i * 16 + l16) * 128 + xa);
      #pragma unroll
      for (int mt = 0; mt < MT; mt++)
        #pragma unroll
        for (int nt = 0; nt < NT; nt++)
          acc[mt][nt] = __builtin_amdgcn_mfma_f32_16x16x32_bf16(af[mt], bfr[nt], acc[mt][nt], 0, 0, 0);
    }
    __syncthreads();
    cur ^= 1;
  }

  #pragma unroll
  for (int mt = 0; mt < MT; mt++){
    #pragma unroll
    for (int nt = 0; nt < NT; nt++){
      #pragma unroll
      for (int r = 0; r < 4; r++){
        int m = m_blk + wm + mt * 16 + quad * 4 + r;
        int n = n_blk + wn + nt * 16 + l16;
        float v = acc[mt][nt][r];
        if (EPI == 0){
          ((float*)Cout)[(size_t)m * ldc + n] = v;
        } else if (EPI == 1){
          ((__hip_bfloat16*)Cout)[(size_t)m * ldc + n] = __float2bfloat16(siluf(v));
        } else {
          if (n < 2048)      ((ushort_t*)Cout)[(size_t)m * ldc + n] = f2bf(softplusf(v + bias[n]));
          else if (n < 2064) Bm[(size_t)m * 16 + (n - 2048)] = v;
          else if (n < 2080) Cm[(size_t)m * 16 + (n - 2064)] = v;
        }
      }
    }
  }
}

// An2 = -exp(A_log) * log2(e): use exp2f downstream (R15 — kills the v_mul
// inside __expf; 16 muls/row across scan1/scan2/combine).
__device__ __forceinline__ void load_An(const float* A_log, int d, float* An){
  const float* ap = A_log + (size_t)d * 16;
  #pragma unroll
  for (int j = 0; j < 16; j += 4){
    float4 v = *(const float4*)(ap + j);
    An[j]   = -__expf(v.x) * 1.44269504f;
    An[j+1] = -__expf(v.y) * 1.44269504f;
    An[j+2] = -__expf(v.z) * 1.44269504f;
    An[j+3] = -__expf(v.w) * 1.44269504f;
  }
}

// ---------------- scan pass 1: per-chunk partials (h_in = 0) ----------------
// R14: NC=64 x TC=32, 16-row staging quarters -> LDS 18KB, grid 1024 = 4/CU.
__global__ __launch_bounds__(256) void k_scan1(
    const ushort_t* __restrict__ delta, const ushort_t* __restrict__ U,
    const float* __restrict__ Bm, const float* __restrict__ A_log,
    float* __restrict__ q, float* __restrict__ S)
{
  __shared__ float ldsB[TC * 16];
  __shared__ __align__(16) ushort_t ldsD[16 * 256];
  __shared__ __align__(16) ushort_t ldsU[16 * 256];
  const int tid = threadIdx.x;
  const int bx  = blockIdx.x;
  const int ch  = bx * 256 + tid;
  const int b   = ch >> 11, d = ch & 2047;
  const int d0  = (bx & 7) * 256;
  const int c   = blockIdx.y;
  const int t0  = c * TC;
  {
    int tt = tid >> 3, n2 = (tid & 7) * 2;     // 32 rows x 16: float2/thread
    *(float2*)&ldsB[tt * 16 + n2] = *(const float2*)&Bm[((size_t)b * L_SZ + t0 + tt) * 16 + n2];
  }
  float An[16];
  load_An(A_log, d, An);
  float h[16];
  #pragma unroll
  for (int j = 0; j < 16; j++) h[j] = 0.f;
  float Ssum = 0.f;
  const size_t row0 = (size_t)b * L_SZ + t0;
  const int rr = tid >> 5, cc = (tid & 31) * 8;   // staging: 8 rows/issue
  for (int half = 0; half < 2; half++){
    __syncthreads();          // prev-quarter reads done (and ldsB, 1st iter)
    #pragma unroll
    for (int j = 0; j < 2; j++){
      size_t grow = row0 + half * 16 + j * 8 + rr;
      __builtin_amdgcn_global_load_lds((gas1_t)(const void*)(delta + grow * DI + d0 + cc),
                                       (las3_t)(void*)((char*)ldsD + j * 4096 + tid * 16), 16, 0, 0);
      __builtin_amdgcn_global_load_lds((gas1_t)(const void*)(U + grow * 4096 + d0 + cc),
                                       (las3_t)(void*)((char*)ldsU + j * 4096 + tid * 16), 16, 0, 0);
    }
    __syncthreads();          // drains vmcnt -> staged tiles visible
    #pragma unroll 8
    for (int k = 0; k < 16; k++){
      int row = half * 16 + k;
      float dlt = bf2f(ldsD[k * 256 + tid]);
      float uv  = bf2f(ldsU[k * 256 + tid]);
      float du = dlt * uv;
      Ssum += dlt;
      #pragma unroll
      for (int nn = 0; nn < 16; nn++)
        h[nn] = fmaf(exp2f(dlt * An[nn]), h[nn], du * ldsB[row * 16 + nn]);
    }
  }
  size_t qb = ((size_t)c * M_ROWS + ch) * 16;
  #pragma unroll
  for (int j = 0; j < 16; j += 4)
    *(float4*)&q[qb + j] = make_float4(h[j], h[j+1], h[j+2], h[j+3]);
  S[(size_t)c * M_ROWS + ch] = Ssum;
}

// ---------------- scan combine: sequential over chunks ----------------
__global__ __launch_bounds__(256) void k_scan_combine(
    const float* __restrict__ q, const float* __restrict__ S,
    const float* __restrict__ A_log, float* __restrict__ hin)
{
  int gid = blockIdx.x * 256 + threadIdx.x;      // 65536 = 4096 ch * 16 n
  int ch = gid >> 4, nn = gid & 15, d = ch & 2047;
  float An = -__expf(A_log[(size_t)d * 16 + nn]) * 1.44269504f;
  float h = 0.f;
  for (int c = 0; c < NC; c++){
    size_t base = (size_t)c * M_ROWS + ch;
    hin[base * 16 + nn] = h;
    h = fmaf(exp2f(An * S[base]), h, q[base * 16 + nn]);
  }
}

// ---------------- scan pass 2: replay with h_in, emit y ----------------
// R14: NC=64 x TC=32, 16-row quarters -> LDS 28KB, grid 1024 = 4/CU.
__global__ __launch_bounds__(256) void k_scan2(
    const ushort_t* __restrict__ delta, const ushort_t* __restrict__ U,
    const float* __restrict__ Bm, const float* __restrict__ Cm,
    const float* __restrict__ A_log, const float* __restrict__ Dpar,
    const float* __restrict__ hin, ushort_t* __restrict__ Y)
{
  __shared__ float ldsBC[TC * 16 * 2];
  __shared__ __align__(16) ushort_t ldsD[16 * 256];
  __shared__ __align__(16) ushort_t ldsU[16 * 256];
  __shared__ __align__(16) ushort_t ldsR[16 * 256];
  const int tid = threadIdx.x;
  const int bx  = blockIdx.x;
  const int ch  = bx * 256 + tid;
  const int b   = ch >> 11, d = ch & 2047;
  const int d0  = (bx & 7) * 256;
  const int c   = blockIdx.y;
  const int t0  = c * TC;
  {
    int tt = tid >> 3, n2 = (tid & 7) * 2;     // 32 rows x 16 cols, 2/thread
    size_t gb = ((size_t)b * L_SZ + t0 + tt) * 16 + n2;
    float2 bv = *(const float2*)&Bm[gb];
    float2 cv = *(const float2*)&Cm[gb];
    float2* dst = (float2*)&ldsBC[(tt * 16 + n2) * 2];
    dst[0] = make_float2(bv.x, cv.x);
    dst[1] = make_float2(bv.y, cv.y);
  }
  float An[16];
  load_An(A_log, d, An);
  float Dv = Dpar[d];
  float h[16];
  size_t hb = ((size_t)c * M_ROWS + ch) * 16;
  #pragma unroll
  for (int j = 0; j < 16; j += 4){
    float4 hv = *(const float4*)&hin[hb + j];
    h[j] = hv.x; h[j+1] = hv.y; h[j+2] = hv.z; h[j+3] = hv.w;
  }
  const size_t row0 = (size_t)b * L_SZ + t0;
  const int rr = tid >> 5, cc = (tid & 31) * 8;
  for (int half = 0; half < 2; half++){
    __syncthreads();          // prev-quarter reads done (and ldsBC, 1st iter)
    #pragma unroll
    for (int j = 0; j < 2; j++){
      size_t grow = row0 + half * 16 + j * 8 + rr;
      __builtin_amdgcn_global_load_lds((gas1_t)(const void*)(delta + grow * DI + d0 + cc),
                                       (las3_t)(void*)((char*)ldsD + j * 4096 + tid * 16), 16, 0, 0);
      __builtin_amdgcn_global_load_lds((gas1_t)(const void*)(U + grow * 4096 + d0 + cc),
                                       (las3_t)(void*)((char*)ldsU + j * 4096 + tid * 16), 16, 0, 0);
      __builtin_amdgcn_global_load_lds((gas1_t)(const void*)(U + grow * 4096 + 2048 + d0 + cc),
                                       (las3_t)(void*)((char*)ldsR + j * 4096 + tid * 16), 16, 0, 0);
    }
    __syncthreads();          // drains vmcnt
    #pragma unroll 8
    for (int k = 0; k < 16; k++){
      int row = half * 16 + k;
      float dlt  = bf2f(ldsD[k * 256 + tid]);
      float uv   = bf2f(ldsU[k * 256 + tid]);
      float sres = bf2f(ldsR[k * 256 + tid]);
      float du = dlt * uv;
      float y = 0.f;
      #pragma unroll
      for (int nn = 0; nn < 16; nn++){
        float2 bc = *(const float2*)&ldsBC[(row * 16 + nn) * 2];
        h[nn] = fmaf(exp2f(dlt * An[nn]), h[nn], du * bc.x);
        y = fmaf(h[nn], bc.y, y);
      }
      Y[(row0 + row) * DI + d] = f2bf((y + uv * Dv) * sres);
    }
  }
}

extern "C" void kernel_launch(void* const* d_in, const int* in_sizes, int n_in,
                              void* d_out, int out_size, void* d_ws, size_t ws_size,
                              hipStream_t stream)
{
  const float* x       = (const float*)d_in[0];
  const float* W_in    = (const float*)d_in[1];
  const float* W_delta = (const float*)d_in[2];
  const float* b_delta = (const float*)d_in[3];
  const float* W_B     = (const float*)d_in[4];
  const float* W_C     = (const float*)d_in[5];
  const float* A_log   = (const float*)d_in[6];
  const float* D_par   = (const float*)d_in[7];
  const float* W_out   = (const float*)d_in[8];

  char* ws = (char*)d_ws;
  size_t off = 0;
  auto alloc = [&](size_t bytes){ char* p = ws + off; off += (bytes + 255) & ~(size_t)255; return p; };
  ushort_t* W_inT  = (ushort_t*)alloc((size_t)4096*1024*2);
  ushort_t* W_bigT = (ushort_t*)alloc((size_t)2304*2048*2);   // rows 0..2175 init'd
  ushort_t* W_outT = (ushort_t*)alloc((size_t)1024*2048*2);
  ushort_t* xb     = (ushort_t*)alloc((size_t)4096*1024*2);
  ushort_t* U      = (ushort_t*)alloc((size_t)4096*4096*2);
  ushort_t* dl     = (ushort_t*)alloc((size_t)4096*2048*2);
  float*    Bm     = (float*)alloc((size_t)4096*16*4);
  float*    Cm     = (float*)alloc((size_t)4096*16*4);
  float*    qbuf   = (float*)alloc((size_t)NC*4096*16*4);
  float*    Sbuf   = (float*)alloc((size_t)NC*4096*4);
  float*    hin    = (float*)alloc((size_t)NC*4096*16*4);
  ushort_t* Y      = (ushort_t*)alloc((size_t)4096*2048*2);

  // 1) fused prep (incl. zero-fill of W_bigT pad rows 2080..2175)
  k_prep<<<dim3(14560),256,0,stream>>>(W_in, W_delta, W_out, W_B, W_C, x,
                                       W_inT, W_bigT, W_outT, xb);

  // 2) GEMM1: U = silu(x @ W_in) — 256x256 2-buf, 512 thr, grid 256 (1/CU)
  k_gemm2p<256,256,512,2,4,1,2><<<dim3(16,16),512,0,stream>>>(
      xb, 1024, W_inT, 1024, U, 4096, nullptr, nullptr, nullptr, 1024);

  // 3) GEMM2 as two M-halves (R15 diagnostic — re-expose post-R14 ranking).
  //    Each: M rows [0,2048)/[2048,4096), grid 33x16 = 528 % 8 == 0
  k_gemm2p<128,64,256,2,2,2,3><<<dim3(33,16),256,0,stream>>>(
      U, 4096, W_bigT, 2048, dl, 2048, b_delta, Bm, Cm, 2048);
  k_gemm2p<128,64,256,2,2,2,3><<<dim3(33,16),256,0,stream>>>(
      U + (size_t)2048*4096, 4096, W_bigT, 2048,
      (void*)((ushort_t*)dl + (size_t)2048*2048), 2048, b_delta,
      Bm + (size_t)2048*16, Cm + (size_t)2048*16, 2048);

  // 4-6) chunked selective scan (NC=64 x TC=32, 4 blk/CU; exp2f — R15)
  k_scan1<<<dim3(16,NC),256,0,stream>>>(dl, U, Bm, A_log, qbuf, Sbuf);
  k_scan_combine<<<dim3(256),256,0,stream>>>(qbuf, Sbuf, A_log, hin);
  k_scan2<<<dim3(16,NC),256,0,stream>>>(dl, U, Bm, Cm, A_log, D_par, hin, Y);

  // 7) GEMM3: out = Y @ W_out (fp32) — 128x64 2-buf, MINW=3, grid 512
  k_gemm2p<128,64,256,2,2,0,3><<<dim3(16,32),256,0,stream>>>(
      Y, 2048, W_outT, 2048, d_out, 1024, nullptr, nullptr, nullptr, 2048);
}

// Round 16
// 308.288 us; speedup vs baseline: 1.1544x; 1.1544x over previous
//
#include <hip/hip_runtime.h>
#include <hip/hip_bf16.h>

typedef unsigned short ushort_t;
typedef __bf16 bf16x8 __attribute__((ext_vector_type(8)));
typedef float f32x4 __attribute__((ext_vector_type(4)));

typedef const void __attribute__((address_space(1)))* gas1_t;
typedef void __attribute__((address_space(3)))* las3_t;

#define L_SZ 2048
#define DI   2048
#define M_ROWS 4096
#define NC 64
#define TC 32

__device__ __forceinline__ float bf2f(ushort_t u){
  unsigned x = ((unsigned)u) << 16; float f; __builtin_memcpy(&f, &x, 4); return f;
}
__device__ __forceinline__ ushort_t f2bf(float f){
  __hip_bfloat16 h = __float2bfloat16(f);
  ushort_t u; __builtin_memcpy(&u, &h, 2); return u;
}
__device__ __forceinline__ float siluf(float x){ return x / (1.0f + __expf(-x)); }
__device__ __forceinline__ float softplusf(float x){
  return (x > 20.0f) ? x : log1pf(__expf(x));
}
// raw v_exp_f32 (no OCML wrapper)
#define EXP2(x) __builtin_amdgcn_exp2f(x)

// ---------------- fused prep: all weight transposes + x cast, ONE launch ----
// ids [0,10368): transposes; [10368,14464): x cast; [14464,14560): zero-fill
// W_bigT pad rows 2080..2175 (GEMM2 N padded to 33x64 = 2112).
__global__ __launch_bounds__(256) void k_prep(
    const float* __restrict__ W_in, const float* __restrict__ W_delta,
    const float* __restrict__ W_out, const float* __restrict__ W_B,
    const float* __restrict__ W_C, const float* __restrict__ x,
    ushort_t* __restrict__ W_inT, ushort_t* __restrict__ W_bigT,
    ushort_t* __restrict__ W_outT, ushort_t* __restrict__ xb)
{
  int t = blockIdx.x;
  if (t >= 14464){
    int r = 2080 + (t - 14464);
    uint4 z = make_uint4(0,0,0,0);
    *(uint4*)(W_bigT + (size_t)r * 2048 + threadIdx.x * 8) = z;
    return;
  }
  if (t >= 10368){
    size_t i = (size_t)(t - 10368) * 256 + threadIdx.x;
    float4 v = *(const float4*)(x + i * 4);
    ushort_t o[4] = { f2bf(v.x), f2bf(v.y), f2bf(v.z), f2bf(v.w) };
    *(uint2*)(xb + i * 4) = *(const uint2*)o;
    return;
  }
  const float* in; ushort_t* out; int R, C, tx, ty;
  if (t < 4096)      { in=W_in;    out=W_inT;  R=1024; C=4096; tx = t & 127; ty = t >> 7; }
  else if (t < 8192) { t -= 4096;  in=W_delta; out=W_bigT; R=2048; C=2048; tx = t & 63; ty = t >> 6; }
  else if (t < 10240){ t -= 8192;  in=W_out;   out=W_outT; R=2048; C=1024; tx = t & 31; ty = t >> 5; }
  else if (t < 10304){ t -= 10240; in=W_B;  out=W_bigT + (size_t)2048*2048; R=2048; C=16; tx=0; ty=t; }
  else               { t -= 10304; in=W_C;  out=W_bigT + (size_t)2064*2048; R=2048; C=16; tx=0; ty=t; }
  __shared__ ushort_t tile[32][33];
  int c0 = tx * 32, r0 = ty * 32;
  int xx = threadIdx.x & 31, yy = threadIdx.x >> 5;
  #pragma unroll
  for (int i = 0; i < 32; i += 8){
    int r = r0 + yy + i, c = c0 + xx;
    if (r < R && c < C) tile[yy + i][xx] = f2bf(in[(size_t)r * C + c]);
  }
  __syncthreads();
  #pragma unroll
  for (int i = 0; i < 32; i += 8){
    int c = c0 + yy + i, r = r0 + xx;
    if (r < R && c < C) out[(size_t)c * R + r] = tile[xx][yy + i];
  }
}

// ------------- 2-phase double-buffered GEMM: C = A[M,K] * Bt[N,K]^T --------
// CONVERGED core (R0-R11 search): BK=64, STAGE(buf^1,t+1) before compute, one
// __syncthreads per K-step; XOR-swizzled LDS via pre-swizzled source
// (conflicts=0); T1 XCD-chunked blockIdx swizzle (grid % 8 == 0).
// GEMM1 256x256/512thr/1 blk/CU; GEMM2/3 128x64/256thr/3 blk/CU.
// EPI: 0=fp32 store, 1=silu->bf16, 2=softplus(+bias)->bf16 + fused Bm/Cm
// at n in [2048,2080), discard n >= 2080 (padded N).
template<int BM, int BN, int TPB, int WR, int WC, int EPI, int MINW>
__global__ __launch_bounds__(TPB, MINW) void k_gemm2p(
    const ushort_t* __restrict__ A, int lda,
    const ushort_t* __restrict__ Bt, int ldb,
    void* __restrict__ Cout, int ldc,
    const float* __restrict__ bias,
    float* __restrict__ Bm, float* __restrict__ Cm, int K)
{
  constexpr int WM = BM / WR, WN = BN / WC;
  constexpr int MT = WM / 16, NT = WN / 16;
  constexpr int BUFSZ = (BM + BN) * 128;        // one K-step buffer (BK=64)
  constexpr int ACH = BM * 8;                   // 16B chunks of A per buffer
  constexpr int NISSUE = (BM + BN) * 8 / TPB;
  __shared__ __align__(16) char lds[2 * BUFSZ];
  const int tid  = threadIdx.x;
  const int wave = tid >> 6, lane = tid & 63;
  const int quad = lane >> 4, l16 = lane & 15;

  // T1: bijective XCD-chunked swizzle (gridDim.x*gridDim.y % 8 == 0)
  const int gx  = gridDim.x;
  const int nwg = gx * gridDim.y;
  const int bid = blockIdx.y * gx + blockIdx.x;
  const int cpx = nwg >> 3;
  const int wid = (bid & 7) * cpx + (bid >> 3);
  const int bx  = wid % gx, by = wid / gx;

  const int m_blk = by * BM, n_blk = bx * BN;
  const int wm = (wave / WC) * WM, wn = (wave % WC) * WN;

  f32x4 acc[MT][NT] = {};

  const ushort_t* gptr[NISSUE];
  char* lptr[NISSUE];
  #pragma unroll
  for (int i = 0; i < NISSUE; i++){
    int g = tid + i * TPB;
    if (g < ACH){
      int row = g >> 3, c = g & 7;
      gptr[i] = A + (size_t)(m_blk + row) * lda + ((c ^ (row & 7)) * 8);
    } else {
      int gb = g - ACH;
      int row = gb >> 3, c = gb & 7;
      gptr[i] = Bt + (size_t)(n_blk + row) * ldb + ((c ^ (row & 7)) * 8);
    }
    lptr[i] = lds + (size_t)g * 16;
  }

  const int xsw = (l16 & 7);
  const int NSTEP = K >> 6;

  #pragma unroll
  for (int i = 0; i < NISSUE; i++)
    __builtin_amdgcn_global_load_lds((gas1_t)(const void*)gptr[i], (las3_t)lptr[i], 16, 0, 0);
  __syncthreads();

  int cur = 0;
  for (int t = 0; t < NSTEP; ++t){
    if (t + 1 < NSTEP){
      const int nxt = (cur ^ 1) * BUFSZ;
      #pragma unroll
      for (int i = 0; i < NISSUE; i++)
        __builtin_amdgcn_global_load_lds((gas1_t)(const void*)(gptr[i] + (t + 1) * 64),
                                         (las3_t)(lptr[i] + nxt), 16, 0, 0);
    }
    const char* ldsA = lds + cur * BUFSZ;
    const char* ldsB = ldsA + BM * 128;
    #pragma unroll
    for (int s = 0; s < 2; s++){
      const int xa = ((s * 4 + quad) ^ xsw) * 16;
      bf16x8 af[MT], bfr[NT];
      #pragma unroll
      for (int i = 0; i < MT; i++)
        af[i]  = *(const bf16x8*)(ldsA + (wm + i * 16 + l16) * 128 + xa);
      #pragma unroll
      for (int i = 0; i < NT; i++)
        bfr[i] = *(const bf16x8*)(ldsB + (wn + i * 16 + l16) * 128 + xa);
      #pragma unroll
      for (int mt = 0; mt < MT; mt++)
        #pragma unroll
        for (int nt = 0; nt < NT; nt++)
          acc[mt][nt] = __builtin_amdgcn_mfma_f32_16x16x32_bf16(af[mt], bfr[nt], acc[mt][nt], 0, 0, 0);
    }
    __syncthreads();
    cur ^= 1;
  }

  #pragma unroll
  for (int mt = 0; mt < MT; mt++){
    #pragma unroll
    for (int nt = 0; nt < NT; nt++){
      #pragma unroll
      for (int r = 0; r < 4; r++){
        int m = m_blk + wm + mt * 16 + quad * 4 + r;
        int n = n_blk + wn + nt * 16 + l16;
        float v = acc[mt][nt][r];
        if (EPI == 0){
          ((float*)Cout)[(size_t)m * ldc + n] = v;
        } else if (EPI == 1){
          ((__hip_bfloat16*)Cout)[(size_t)m * ldc + n] = __float2bfloat16(siluf(v));
        } else {
          if (n < 2048)      ((ushort_t*)Cout)[(size_t)m * ldc + n] = f2bf(softplusf(v + bias[n]));
          else if (n < 2064) Bm[(size_t)m * 16 + (n - 2048)] = v;
          else if (n < 2080) Cm[(size_t)m * 16 + (n - 2064)] = v;
        }
      }
    }
  }
}

// An2 = -exp(A_log) * log2(e): exp2-domain decay rates.
__device__ __forceinline__ void load_An(const float* A_log, int d, float* An){
  const float* ap = A_log + (size_t)d * 16;
  #pragma unroll
  for (int j = 0; j < 16; j += 4){
    float4 v = *(const float4*)(ap + j);
    An[j]   = -__expf(v.x) * 1.44269504f;
    An[j+1] = -__expf(v.y) * 1.44269504f;
    An[j+2] = -__expf(v.z) * 1.44269504f;
    An[j+3] = -__expf(v.w) * 1.44269504f;
  }
}

// R16: runtime structure check — An[nn] == (nn+1)*An[0] (holds for the
// A_log = log(arange(1..17)) setup). Wave-uniform; enables the geometric
// fast path (1 exp2 + 15 muls instead of 16 muls + 16 exp2 per timestep,
// ~half the scan's VALU work — scan2 measured 73% VALUBusy, exp-dominated).
__device__ __forceinline__ bool an_geometric(const float* An){
  bool g = true;
  #pragma unroll
  for (int nn = 1; nn < 16; nn++)
    g = g && (fabsf(An[nn] - (float)(nn + 1) * An[0]) <= 1e-4f * fabsf(An[nn]));
  return g;
}

// ---------------- scan pass 1: per-chunk partials (h_in = 0) ----------------
// NC=64 x TC=32, 16-row staging quarters, LDS 18KB, grid 1024 = 4 blk/CU.
__global__ __launch_bounds__(256) void k_scan1(
    const ushort_t* __restrict__ delta, const ushort_t* __restrict__ U,
    const float* __restrict__ Bm, const float* __restrict__ A_log,
    float* __restrict__ q, float* __restrict__ S)
{
  __shared__ float ldsB[TC * 16];
  __shared__ __align__(16) ushort_t ldsD[16 * 256];
  __shared__ __align__(16) ushort_t ldsU[16 * 256];
  const int tid = threadIdx.x;
  const int bx  = blockIdx.x;
  const int ch  = bx * 256 + tid;
  const int b   = ch >> 11, d = ch & 2047;
  const int d0  = (bx & 7) * 256;
  const int c   = blockIdx.y;
  const int t0  = c * TC;
  {
    int tt = tid >> 3, n2 = (tid & 7) * 2;
    *(float2*)&ldsB[tt * 16 + n2] = *(const float2*)&Bm[((size_t)b * L_SZ + t0 + tt) * 16 + n2];
  }
  float An[16];
  load_An(A_log, d, An);
  const bool geo = an_geometric(An);
  float h[16];
  #pragma unroll
  for (int j = 0; j < 16; j++) h[j] = 0.f;
  float Ssum = 0.f;
  const size_t row0 = (size_t)b * L_SZ + t0;
  const int rr = tid >> 5, cc = (tid & 31) * 8;
  for (int half = 0; half < 2; half++){
    __syncthreads();
    #pragma unroll
    for (int j = 0; j < 2; j++){
      size_t grow = row0 + half * 16 + j * 8 + rr;
      __builtin_amdgcn_global_load_lds((gas1_t)(const void*)(delta + grow * DI + d0 + cc),
                                       (las3_t)(void*)((char*)ldsD + j * 4096 + tid * 16), 16, 0, 0);
      __builtin_amdgcn_global_load_lds((gas1_t)(const void*)(U + grow * 4096 + d0 + cc),
                                       (las3_t)(void*)((char*)ldsU + j * 4096 + tid * 16), 16, 0, 0);
    }
    __syncthreads();
    if (geo){
      #pragma unroll 8
      for (int k = 0; k < 16; k++){
        int row = half * 16 + k;
        float dlt = bf2f(ldsD[k * 256 + tid]);
        float uv  = bf2f(ldsU[k * 256 + tid]);
        float du = dlt * uv;
        Ssum += dlt;
        float r = EXP2(dlt * An[0]);
        float e = r;
        #pragma unroll
        for (int nn = 0; nn < 16; nn++){
          h[nn] = fmaf(e, h[nn], du * ldsB[row * 16 + nn]);
          e *= r;
        }
      }
    } else {
      #pragma unroll 8
      for (int k = 0; k < 16; k++){
        int row = half * 16 + k;
        float dlt = bf2f(ldsD[k * 256 + tid]);
        float uv  = bf2f(ldsU[k * 256 + tid]);
        float du = dlt * uv;
        Ssum += dlt;
        #pragma unroll
        for (int nn = 0; nn < 16; nn++)
          h[nn] = fmaf(EXP2(dlt * An[nn]), h[nn], du * ldsB[row * 16 + nn]);
      }
    }
  }
  size_t qb = ((size_t)c * M_ROWS + ch) * 16;
  #pragma unroll
  for (int j = 0; j < 16; j += 4)
    *(float4*)&q[qb + j] = make_float4(h[j], h[j+1], h[j+2], h[j+3]);
  S[(size_t)c * M_ROWS + ch] = Ssum;
}

// ---------------- scan combine: sequential over chunks ----------------
__global__ __launch_bounds__(256) void k_scan_combine(
    const float* __restrict__ q, const float* __restrict__ S,
    const float* __restrict__ A_log, float* __restrict__ hin)
{
  int gid = blockIdx.x * 256 + threadIdx.x;      // 65536 = 4096 ch * 16 n
  int ch = gid >> 4, nn = gid & 15, d = ch & 2047;
  float An = -__expf(A_log[(size_t)d * 16 + nn]) * 1.44269504f;
  float h = 0.f;
  for (int c = 0; c < NC; c++){
    size_t base = (size_t)c * M_ROWS + ch;
    hin[base * 16 + nn] = h;
    h = fmaf(EXP2(An * S[base]), h, q[base * 16 + nn]);
  }
}

// ---------------- scan pass 2: replay with h_in, emit y ----------------
// NC=64 x TC=32, 16-row quarters, LDS 28KB, grid 1024 = 4 blk/CU.
__global__ __launch_bounds__(256) void k_scan2(
    const ushort_t* __restrict__ delta, const ushort_t* __restrict__ U,
    const float* __restrict__ Bm, const float* __restrict__ Cm,
    const float* __restrict__ A_log, const float* __restrict__ Dpar,
    const float* __restrict__ hin, ushort_t* __restrict__ Y)
{
  __shared__ float ldsBC[TC * 16 * 2];
  __shared__ __align__(16) ushort_t ldsD[16 * 256];
  __shared__ __align__(16) ushort_t ldsU[16 * 256];
  __shared__ __align__(16) ushort_t ldsR[16 * 256];
  const int tid = threadIdx.x;
  const int bx  = blockIdx.x;
  const int ch  = bx * 256 + tid;
  const int b   = ch >> 11, d = ch & 2047;
  const int d0  = (bx & 7) * 256;
  const int c   = blockIdx.y;
  const int t0  = c * TC;
  {
    int tt = tid >> 3, n2 = (tid & 7) * 2;
    size_t gb = ((size_t)b * L_SZ + t0 + tt) * 16 + n2;
    float2 bv = *(const float2*)&Bm[gb];
    float2 cv = *(const float2*)&Cm[gb];
    float2* dst = (float2*)&ldsBC[(tt * 16 + n2) * 2];
    dst[0] = make_float2(bv.x, cv.x);
    dst[1] = make_float2(bv.y, cv.y);
  }
  float An[16];
  load_An(A_log, d, An);
  const bool geo = an_geometric(An);
  float Dv = Dpar[d];
  float h[16];
  size_t hb = ((size_t)c * M_ROWS + ch) * 16;
  #pragma unroll
  for (int j = 0; j < 16; j += 4){
    float4 hv = *(const float4*)&hin[hb + j];
    h[j] = hv.x; h[j+1] = hv.y; h[j+2] = hv.z; h[j+3] = hv.w;
  }
  const size_t row0 = (size_t)b * L_SZ + t0;
  const int rr = tid >> 5, cc = (tid & 31) * 8;
  for (int half = 0; half < 2; half++){
    __syncthreads();
    #pragma unroll
    for (int j = 0; j < 2; j++){
      size_t grow = row0 + half * 16 + j * 8 + rr;
      __builtin_amdgcn_global_load_lds((gas1_t)(const void*)(delta + grow * DI + d0 + cc),
                                       (las3_t)(void*)((char*)ldsD + j * 4096 + tid * 16), 16, 0, 0);
      __builtin_amdgcn_global_load_lds((gas1_t)(const void*)(U + grow * 4096 + d0 + cc),
                                       (las3_t)(void*)((char*)ldsU + j * 4096 + tid * 16), 16, 0, 0);
      __builtin_amdgcn_global_load_lds((gas1_t)(const void*)(U + grow * 4096 + 2048 + d0 + cc),
                                       (las3_t)(void*)((char*)ldsR + j * 4096 + tid * 16), 16, 0, 0);
    }
    __syncthreads();
    if (geo){
      #pragma unroll 8
      for (int k = 0; k < 16; k++){
        int row = half * 16 + k;
        float dlt  = bf2f(ldsD[k * 256 + tid]);
        float uv   = bf2f(ldsU[k * 256 + tid]);
        float sres = bf2f(ldsR[k * 256 + tid]);
        float du = dlt * uv;
        float y = 0.f;
        float r = EXP2(dlt * An[0]);
        float e = r;
        #pragma unroll
        for (int nn = 0; nn < 16; nn++){
          float2 bc = *(const float2*)&ldsBC[(row * 16 + nn) * 2];
          h[nn] = fmaf(e, h[nn], du * bc.x);
          y = fmaf(h[nn], bc.y, y);
          e *= r;
        }
        Y[(row0 + row) * DI + d] = f2bf((y + uv * Dv) * sres);
      }
    } else {
      #pragma unroll 8
      for (int k = 0; k < 16; k++){
        int row = half * 16 + k;
        float dlt  = bf2f(ldsD[k * 256 + tid]);
        float uv   = bf2f(ldsU[k * 256 + tid]);
        float sres = bf2f(ldsR[k * 256 + tid]);
        float du = dlt * uv;
        float y = 0.f;
        #pragma unroll
        for (int nn = 0; nn < 16; nn++){
          float2 bc = *(const float2*)&ldsBC[(row * 16 + nn) * 2];
          h[nn] = fmaf(EXP2(dlt * An[nn]), h[nn], du * bc.x);
          y = fmaf(h[nn], bc.y, y);
        }
        Y[(row0 + row) * DI + d] = f2bf((y + uv * Dv) * sres);
      }
    }
  }
}

extern "C" void kernel_launch(void* const* d_in, const int* in_sizes, int n_in,
                              void* d_out, int out_size, void* d_ws, size_t ws_size,
                              hipStream_t stream)
{
  const float* x       = (const float*)d_in[0];
  const float* W_in    = (const float*)d_in[1];
  const float* W_delta = (const float*)d_in[2];
  const float* b_delta = (const float*)d_in[3];
  const float* W_B     = (const float*)d_in[4];
  const float* W_C     = (const float*)d_in[5];
  const float* A_log   = (const float*)d_in[6];
  const float* D_par   = (const float*)d_in[7];
  const float* W_out   = (const float*)d_in[8];

  char* ws = (char*)d_ws;
  size_t off = 0;
  auto alloc = [&](size_t bytes){ char* p = ws + off; off += (bytes + 255) & ~(size_t)255; return p; };
  ushort_t* W_inT  = (ushort_t*)alloc((size_t)4096*1024*2);
  ushort_t* W_bigT = (ushort_t*)alloc((size_t)2304*2048*2);   // rows 0..2175 init'd
  ushort_t* W_outT = (ushort_t*)alloc((size_t)1024*2048*2);
  ushort_t* xb     = (ushort_t*)alloc((size_t)4096*1024*2);
  ushort_t* U      = (ushort_t*)alloc((size_t)4096*4096*2);
  ushort_t* dl     = (ushort_t*)alloc((size_t)4096*2048*2);
  float*    Bm     = (float*)alloc((size_t)4096*16*4);
  float*    Cm     = (float*)alloc((size_t)4096*16*4);
  float*    qbuf   = (float*)alloc((size_t)NC*4096*16*4);
  float*    Sbuf   = (float*)alloc((size_t)NC*4096*4);
  float*    hin    = (float*)alloc((size_t)NC*4096*16*4);
  ushort_t* Y      = (ushort_t*)alloc((size_t)4096*2048*2);

  // 1) fused prep (incl. zero-fill of W_bigT pad rows 2080..2175)
  k_prep<<<dim3(14560),256,0,stream>>>(W_in, W_delta, W_out, W_B, W_C, x,
                                       W_inT, W_bigT, W_outT, xb);

  // 2) GEMM1: U = silu(x @ W_in) — 256x256 2-buf, 512 thr, grid 256 (1/CU)
  k_gemm2p<256,256,512,2,4,1,2><<<dim3(16,16),512,0,stream>>>(
      xb, 1024, W_inT, 1024, U, 4096, nullptr, nullptr, nullptr, 1024);

  // 3) GEMM2: dl = softplus(u@W_delta+b), fused Bm/Cm — 128x64 2-buf,
  //    MINW=3 (3 blk/CU); N padded to 2112 (33 N-blocks); grid 1056 % 8 == 0
  //    (merged back — R15 diagnostic done: ranking = GEMM2 86.5 > scan2 53)
  k_gemm2p<128,64,256,2,2,2,3><<<dim3(33,32),256,0,stream>>>(
      U, 4096, W_bigT, 2048, dl, 2048, b_delta, Bm, Cm, 2048);

  // 4-6) chunked selective scan (NC=64 x TC=32; R16 geometric-exp fast path)
  k_scan1<<<dim3(16,NC),256,0,stream>>>(dl, U, Bm, A_log, qbuf, Sbuf);
  k_scan_combine<<<dim3(256),256,0,stream>>>(qbuf, Sbuf, A_log, hin);
  k_scan2<<<dim3(16,NC),256,0,stream>>>(dl, U, Bm, Cm, A_log, D_par, hin, Y);

  // 7) GEMM3: out = Y @ W_out (fp32) — 128x64 2-buf, MINW=3, grid 512
  k_gemm2p<128,64,256,2,2,0,3><<<dim3(16,32),256,0,stream>>>(
      Y, 2048, W_outT, 2048, d_out, 1024, nullptr, nullptr, nullptr, 2048);
}

// Round 17
// 300.192 us; speedup vs baseline: 1.1855x; 1.0270x over previous
//
#include <hip/hip_runtime.h>
#include <hip/hip_bf16.h>

typedef unsigned short ushort_t;
typedef __bf16 bf16x8 __attribute__((ext_vector_type(8)));
typedef float f32x4 __attribute__((ext_vector_type(4)));

typedef const void __attribute__((address_space(1)))* gas1_t;
typedef void __attribute__((address_space(3)))* las3_t;

#define L_SZ 2048
#define DI   2048
#define M_ROWS 4096
#define NC 64
#define TC 32

__device__ __forceinline__ float bf2f(ushort_t u){
  unsigned x = ((unsigned)u) << 16; float f; __builtin_memcpy(&f, &x, 4); return f;
}
__device__ __forceinline__ ushort_t f2bf(float f){
  __hip_bfloat16 h = __float2bfloat16(f);
  ushort_t u; __builtin_memcpy(&u, &h, 2); return u;
}
__device__ __forceinline__ float siluf(float x){ return x / (1.0f + __expf(-x)); }
__device__ __forceinline__ float softplusf(float x){
  return (x > 20.0f) ? x : log1pf(__expf(x));
}
// raw v_exp_f32 (no OCML wrapper)
#define EXP2(x) __builtin_amdgcn_exp2f(x)

// ---------------- fused prep: all weight transposes + x cast, ONE launch ----
// ids [0,10368): transposes; [10368,14464): x cast; [14464,14560): zero-fill
// W_bigT pad rows 2080..2175 (GEMM2 N padded to 33x64 = 2112).
__global__ __launch_bounds__(256) void k_prep(
    const float* __restrict__ W_in, const float* __restrict__ W_delta,
    const float* __restrict__ W_out, const float* __restrict__ W_B,
    const float* __restrict__ W_C, const float* __restrict__ x,
    ushort_t* __restrict__ W_inT, ushort_t* __restrict__ W_bigT,
    ushort_t* __restrict__ W_outT, ushort_t* __restrict__ xb)
{
  int t = blockIdx.x;
  if (t >= 14464){
    int r = 2080 + (t - 14464);
    uint4 z = make_uint4(0,0,0,0);
    *(uint4*)(W_bigT + (size_t)r * 2048 + threadIdx.x * 8) = z;
    return;
  }
  if (t >= 10368){
    size_t i = (size_t)(t - 10368) * 256 + threadIdx.x;
    float4 v = *(const float4*)(x + i * 4);
    ushort_t o[4] = { f2bf(v.x), f2bf(v.y), f2bf(v.z), f2bf(v.w) };
    *(uint2*)(xb + i * 4) = *(const uint2*)o;
    return;
  }
  const float* in; ushort_t* out; int R, C, tx, ty;
  if (t < 4096)      { in=W_in;    out=W_inT;  R=1024; C=4096; tx = t & 127; ty = t >> 7; }
  else if (t < 8192) { t -= 4096;  in=W_delta; out=W_bigT; R=2048; C=2048; tx = t & 63; ty = t >> 6; }
  else if (t < 10240){ t -= 8192;  in=W_out;   out=W_outT; R=2048; C=1024; tx = t & 31; ty = t >> 5; }
  else if (t < 10304){ t -= 10240; in=W_B;  out=W_bigT + (size_t)2048*2048; R=2048; C=16; tx=0; ty=t; }
  else               { t -= 10304; in=W_C;  out=W_bigT + (size_t)2064*2048; R=2048; C=16; tx=0; ty=t; }
  __shared__ ushort_t tile[32][33];
  int c0 = tx * 32, r0 = ty * 32;
  int xx = threadIdx.x & 31, yy = threadIdx.x >> 5;
  #pragma unroll
  for (int i = 0; i < 32; i += 8){
    int r = r0 + yy + i, c = c0 + xx;
    if (r < R && c < C) tile[yy + i][xx] = f2bf(in[(size_t)r * C + c]);
  }
  __syncthreads();
  #pragma unroll
  for (int i = 0; i < 32; i += 8){
    int c = c0 + yy + i, r = r0 + xx;
    if (r < R && c < C) out[(size_t)c * R + r] = tile[xx][yy + i];
  }
}

// ------------- 2-phase double-buffered GEMM: C = A[M,K] * Bt[N,K]^T --------
// CONVERGED schedule (R0-R11): BK=64, STAGE(buf^1,t+1) before compute, one
// __syncthreads per K-step; XOR-swizzled LDS via pre-swizzled source
// (conflicts=0); T1 XCD-chunked blockIdx swizzle (grid % 8 == 0).
// R17: GEMM2/3 move 256->512 threads (8 waves, per-wave 32x32, WR x WC=4x2):
// same tile/LDS/barriers, 3 blk/CU -> 24 waves/CU (2x TLP; GEMM2 counters
// showed MfmaUtil 17 / VALU 45 / HBM 14 / occ 23 = wave-starved latency).
// EPI: 0=fp32 store, 1=silu->bf16, 2=softplus(+bias)->bf16 + fused Bm/Cm
// at n in [2048,2080), discard n >= 2080 (padded N).
template<int BM, int BN, int TPB, int WR, int WC, int EPI, int MINW>
__global__ __launch_bounds__(TPB, MINW) void k_gemm2p(
    const ushort_t* __restrict__ A, int lda,
    const ushort_t* __restrict__ Bt, int ldb,
    void* __restrict__ Cout, int ldc,
    const float* __restrict__ bias,
    float* __restrict__ Bm, float* __restrict__ Cm, int K)
{
  constexpr int WM = BM / WR, WN = BN / WC;
  constexpr int MT = WM / 16, NT = WN / 16;
  constexpr int BUFSZ = (BM + BN) * 128;        // one K-step buffer (BK=64)
  constexpr int ACH = BM * 8;                   // 16B chunks of A per buffer
  constexpr int NISSUE = (BM + BN) * 8 / TPB;
  __shared__ __align__(16) char lds[2 * BUFSZ];
  const int tid  = threadIdx.x;
  const int wave = tid >> 6, lane = tid & 63;
  const int quad = lane >> 4, l16 = lane & 15;

  // T1: bijective XCD-chunked swizzle (gridDim.x*gridDim.y % 8 == 0)
  const int gx  = gridDim.x;
  const int nwg = gx * gridDim.y;
  const int bid = blockIdx.y * gx + blockIdx.x;
  const int cpx = nwg >> 3;
  const int wid = (bid & 7) * cpx + (bid >> 3);
  const int bx  = wid % gx, by = wid / gx;

  const int m_blk = by * BM, n_blk = bx * BN;
  const int wm = (wave / WC) * WM, wn = (wave % WC) * WN;

  f32x4 acc[MT][NT] = {};

  const ushort_t* gptr[NISSUE];
  char* lptr[NISSUE];
  #pragma unroll
  for (int i = 0; i < NISSUE; i++){
    int g = tid + i * TPB;
    if (g < ACH){
      int row = g >> 3, c = g & 7;
      gptr[i] = A + (size_t)(m_blk + row) * lda + ((c ^ (row & 7)) * 8);
    } else {
      int gb = g - ACH;
      int row = gb >> 3, c = gb & 7;
      gptr[i] = Bt + (size_t)(n_blk + row) * ldb + ((c ^ (row & 7)) * 8);
    }
    lptr[i] = lds + (size_t)g * 16;
  }

  const int xsw = (l16 & 7);
  const int NSTEP = K >> 6;

  #pragma unroll
  for (int i = 0; i < NISSUE; i++)
    __builtin_amdgcn_global_load_lds((gas1_t)(const void*)gptr[i], (las3_t)lptr[i], 16, 0, 0);
  __syncthreads();

  int cur = 0;
  for (int t = 0; t < NSTEP; ++t){
    if (t + 1 < NSTEP){
      const int nxt = (cur ^ 1) * BUFSZ;
      #pragma unroll
      for (int i = 0; i < NISSUE; i++)
        __builtin_amdgcn_global_load_lds((gas1_t)(const void*)(gptr[i] + (t + 1) * 64),
                                         (las3_t)(lptr[i] + nxt), 16, 0, 0);
    }
    const char* ldsA = lds + cur * BUFSZ;
    const char* ldsB = ldsA + BM * 128;
    #pragma unroll
    for (int s = 0; s < 2; s++){
      const int xa = ((s * 4 + quad) ^ xsw) * 16;
      bf16x8 af[MT], bfr[NT];
      #pragma unroll
      for (int i = 0; i < MT; i++)
        af[i]  = *(const bf16x8*)(ldsA + (wm + i * 16 + l16) * 128 + xa);
      #pragma unroll
      for (int i = 0; i < NT; i++)
        bfr[i] = *(const bf16x8*)(ldsB + (wn + i * 16 + l16) * 128 + xa);
      #pragma unroll
      for (int mt = 0; mt < MT; mt++)
        #pragma unroll
        for (int nt = 0; nt < NT; nt++)
          acc[mt][nt] = __builtin_amdgcn_mfma_f32_16x16x32_bf16(af[mt], bfr[nt], acc[mt][nt], 0, 0, 0);
    }
    __syncthreads();
    cur ^= 1;
  }

  #pragma unroll
  for (int mt = 0; mt < MT; mt++){
    #pragma unroll
    for (int nt = 0; nt < NT; nt++){
      #pragma unroll
      for (int r = 0; r < 4; r++){
        int m = m_blk + wm + mt * 16 + quad * 4 + r;
        int n = n_blk + wn + nt * 16 + l16;
        float v = acc[mt][nt][r];
        if (EPI == 0){
          ((float*)Cout)[(size_t)m * ldc + n] = v;
        } else if (EPI == 1){
          ((__hip_bfloat16*)Cout)[(size_t)m * ldc + n] = __float2bfloat16(siluf(v));
        } else {
          if (n < 2048)      ((ushort_t*)Cout)[(size_t)m * ldc + n] = f2bf(softplusf(v + bias[n]));
          else if (n < 2064) Bm[(size_t)m * 16 + (n - 2048)] = v;
          else if (n < 2080) Cm[(size_t)m * 16 + (n - 2064)] = v;
        }
      }
    }
  }
}

// An2 = -exp(A_log) * log2(e): exp2-domain decay rates.
__device__ __forceinline__ void load_An(const float* A_log, int d, float* An){
  const float* ap = A_log + (size_t)d * 16;
  #pragma unroll
  for (int j = 0; j < 16; j += 4){
    float4 v = *(const float4*)(ap + j);
    An[j]   = -__expf(v.x) * 1.44269504f;
    An[j+1] = -__expf(v.y) * 1.44269504f;
    An[j+2] = -__expf(v.z) * 1.44269504f;
    An[j+3] = -__expf(v.w) * 1.44269504f;
  }
}

// Runtime structure check — An[nn] == (nn+1)*An[0] (holds for the
// A_log = log(arange(1..17)) setup). Wave-uniform; enables the geometric
// fast path (1 exp2 + 15 muls instead of 16 exp2 + 16 muls per timestep).
// R16 measured: −17 us total.
__device__ __forceinline__ bool an_geometric(const float* An){
  bool g = true;
  #pragma unroll
  for (int nn = 1; nn < 16; nn++)
    g = g && (fabsf(An[nn] - (float)(nn + 1) * An[0]) <= 1e-4f * fabsf(An[nn]));
  return g;
}

// ---------------- scan pass 1: per-chunk partials (h_in = 0) ----------------
// NC=64 x TC=32, 16-row staging quarters, LDS 18KB, grid 1024 = 4 blk/CU.
__global__ __launch_bounds__(256) void k_scan1(
    const ushort_t* __restrict__ delta, const ushort_t* __restrict__ U,
    const float* __restrict__ Bm, const float* __restrict__ A_log,
    float* __restrict__ q, float* __restrict__ S)
{
  __shared__ float ldsB[TC * 16];
  __shared__ __align__(16) ushort_t ldsD[16 * 256];
  __shared__ __align__(16) ushort_t ldsU[16 * 256];
  const int tid = threadIdx.x;
  const int bx  = blockIdx.x;
  const int ch  = bx * 256 + tid;
  const int b   = ch >> 11, d = ch & 2047;
  const int d0  = (bx & 7) * 256;
  const int c   = blockIdx.y;
  const int t0  = c * TC;
  {
    int tt = tid >> 3, n2 = (tid & 7) * 2;
    *(float2*)&ldsB[tt * 16 + n2] = *(const float2*)&Bm[((size_t)b * L_SZ + t0 + tt) * 16 + n2];
  }
  float An[16];
  load_An(A_log, d, An);
  const bool geo = an_geometric(An);
  float h[16];
  #pragma unroll
  for (int j = 0; j < 16; j++) h[j] = 0.f;
  float Ssum = 0.f;
  const size_t row0 = (size_t)b * L_SZ + t0;
  const int rr = tid >> 5, cc = (tid & 31) * 8;
  for (int half = 0; half < 2; half++){
    __syncthreads();
    #pragma unroll
    for (int j = 0; j < 2; j++){
      size_t grow = row0 + half * 16 + j * 8 + rr;
      __builtin_amdgcn_global_load_lds((gas1_t)(const void*)(delta + grow * DI + d0 + cc),
                                       (las3_t)(void*)((char*)ldsD + j * 4096 + tid * 16), 16, 0, 0);
      __builtin_amdgcn_global_load_lds((gas1_t)(const void*)(U + grow * 4096 + d0 + cc),
                                       (las3_t)(void*)((char*)ldsU + j * 4096 + tid * 16), 16, 0, 0);
    }
    __syncthreads();
    if (geo){
      #pragma unroll 8
      for (int k = 0; k < 16; k++){
        int row = half * 16 + k;
        float dlt = bf2f(ldsD[k * 256 + tid]);
        float uv  = bf2f(ldsU[k * 256 + tid]);
        float du = dlt * uv;
        Ssum += dlt;
        float r = EXP2(dlt * An[0]);
        float e = r;
        #pragma unroll
        for (int nn = 0; nn < 16; nn++){
          h[nn] = fmaf(e, h[nn], du * ldsB[row * 16 + nn]);
          e *= r;
        }
      }
    } else {
      #pragma unroll 8
      for (int k = 0; k < 16; k++){
        int row = half * 16 + k;
        float dlt = bf2f(ldsD[k * 256 + tid]);
        float uv  = bf2f(ldsU[k * 256 + tid]);
        float du = dlt * uv;
        Ssum += dlt;
        #pragma unroll
        for (int nn = 0; nn < 16; nn++)
          h[nn] = fmaf(EXP2(dlt * An[nn]), h[nn], du * ldsB[row * 16 + nn]);
      }
    }
  }
  size_t qb = ((size_t)c * M_ROWS + ch) * 16;
  #pragma unroll
  for (int j = 0; j < 16; j += 4)
    *(float4*)&q[qb + j] = make_float4(h[j], h[j+1], h[j+2], h[j+3]);
  S[(size_t)c * M_ROWS + ch] = Ssum;
}

// ---------------- scan combine: sequential over chunks ----------------
__global__ __launch_bounds__(256) void k_scan_combine(
    const float* __restrict__ q, const float* __restrict__ S,
    const float* __restrict__ A_log, float* __restrict__ hin)
{
  int gid = blockIdx.x * 256 + threadIdx.x;      // 65536 = 4096 ch * 16 n
  int ch = gid >> 4, nn = gid & 15, d = ch & 2047;
  float An = -__expf(A_log[(size_t)d * 16 + nn]) * 1.44269504f;
  float h = 0.f;
  for (int c = 0; c < NC; c++){
    size_t base = (size_t)c * M_ROWS + ch;
    hin[base * 16 + nn] = h;
    h = fmaf(EXP2(An * S[base]), h, q[base * 16 + nn]);
  }
}

// ---------------- scan pass 2: replay with h_in, emit y ----------------
// NC=64 x TC=32, 16-row quarters, LDS 28KB, grid 1024 = 4 blk/CU.
__global__ __launch_bounds__(256) void k_scan2(
    const ushort_t* __restrict__ delta, const ushort_t* __restrict__ U,
    const float* __restrict__ Bm, const float* __restrict__ Cm,
    const float* __restrict__ A_log, const float* __restrict__ Dpar,
    const float* __restrict__ hin, ushort_t* __restrict__ Y)
{
  __shared__ float ldsBC[TC * 16 * 2];
  __shared__ __align__(16) ushort_t ldsD[16 * 256];
  __shared__ __align__(16) ushort_t ldsU[16 * 256];
  __shared__ __align__(16) ushort_t ldsR[16 * 256];
  const int tid = threadIdx.x;
  const int bx  = blockIdx.x;
  const int ch  = bx * 256 + tid;
  const int b   = ch >> 11, d = ch & 2047;
  const int d0  = (bx & 7) * 256;
  const int c   = blockIdx.y;
  const int t0  = c * TC;
  {
    int tt = tid >> 3, n2 = (tid & 7) * 2;
    size_t gb = ((size_t)b * L_SZ + t0 + tt) * 16 + n2;
    float2 bv = *(const float2*)&Bm[gb];
    float2 cv = *(const float2*)&Cm[gb];
    float2* dst = (float2*)&ldsBC[(tt * 16 + n2) * 2];
    dst[0] = make_float2(bv.x, cv.x);
    dst[1] = make_float2(bv.y, cv.y);
  }
  float An[16];
  load_An(A_log, d, An);
  const bool geo = an_geometric(An);
  float Dv = Dpar[d];
  float h[16];
  size_t hb = ((size_t)c * M_ROWS + ch) * 16;
  #pragma unroll
  for (int j = 0; j < 16; j += 4){
    float4 hv = *(const float4*)&hin[hb + j];
    h[j] = hv.x; h[j+1] = hv.y; h[j+2] = hv.z; h[j+3] = hv.w;
  }
  const size_t row0 = (size_t)b * L_SZ + t0;
  const int rr = tid >> 5, cc = (tid & 31) * 8;
  for (int half = 0; half < 2; half++){
    __syncthreads();
    #pragma unroll
    for (int j = 0; j < 2; j++){
      size_t grow = row0 + half * 16 + j * 8 + rr;
      __builtin_amdgcn_global_load_lds((gas1_t)(const void*)(delta + grow * DI + d0 + cc),
                                       (las3_t)(void*)((char*)ldsD + j * 4096 + tid * 16), 16, 0, 0);
      __builtin_amdgcn_global_load_lds((gas1_t)(const void*)(U + grow * 4096 + d0 + cc),
                                       (las3_t)(void*)((char*)ldsU + j * 4096 + tid * 16), 16, 0, 0);
      __builtin_amdgcn_global_load_lds((gas1_t)(const void*)(U + grow * 4096 + 2048 + d0 + cc),
                                       (las3_t)(void*)((char*)ldsR + j * 4096 + tid * 16), 16, 0, 0);
    }
    __syncthreads();
    if (geo){
      #pragma unroll 8
      for (int k = 0; k < 16; k++){
        int row = half * 16 + k;
        float dlt  = bf2f(ldsD[k * 256 + tid]);
        float uv   = bf2f(ldsU[k * 256 + tid]);
        float sres = bf2f(ldsR[k * 256 + tid]);
        float du = dlt * uv;
        float y = 0.f;
        float r = EXP2(dlt * An[0]);
        float e = r;
        #pragma unroll
        for (int nn = 0; nn < 16; nn++){
          float2 bc = *(const float2*)&ldsBC[(row * 16 + nn) * 2];
          h[nn] = fmaf(e, h[nn], du * bc.x);
          y = fmaf(h[nn], bc.y, y);
          e *= r;
        }
        Y[(row0 + row) * DI + d] = f2bf((y + uv * Dv) * sres);
      }
    } else {
      #pragma unroll 8
      for (int k = 0; k < 16; k++){
        int row = half * 16 + k;
        float dlt  = bf2f(ldsD[k * 256 + tid]);
        float uv   = bf2f(ldsU[k * 256 + tid]);
        float sres = bf2f(ldsR[k * 256 + tid]);
        float du = dlt * uv;
        float y = 0.f;
        #pragma unroll
        for (int nn = 0; nn < 16; nn++){
          float2 bc = *(const float2*)&ldsBC[(row * 16 + nn) * 2];
          h[nn] = fmaf(EXP2(dlt * An[nn]), h[nn], du * bc.x);
          y = fmaf(h[nn], bc.y, y);
        }
        Y[(row0 + row) * DI + d] = f2bf((y + uv * Dv) * sres);
      }
    }
  }
}

extern "C" void kernel_launch(void* const* d_in, const int* in_sizes, int n_in,
                              void* d_out, int out_size, void* d_ws, size_t ws_size,
                              hipStream_t stream)
{
  const float* x       = (const float*)d_in[0];
  const float* W_in    = (const float*)d_in[1];
  const float* W_delta = (const float*)d_in[2];
  const float* b_delta = (const float*)d_in[3];
  const float* W_B     = (const float*)d_in[4];
  const float* W_C     = (const float*)d_in[5];
  const float* A_log   = (const float*)d_in[6];
  const float* D_par   = (const float*)d_in[7];
  const float* W_out   = (const float*)d_in[8];

  char* ws = (char*)d_ws;
  size_t off = 0;
  auto alloc = [&](size_t bytes){ char* p = ws + off; off += (bytes + 255) & ~(size_t)255; return p; };
  ushort_t* W_inT  = (ushort_t*)alloc((size_t)4096*1024*2);
  ushort_t* W_bigT = (ushort_t*)alloc((size_t)2304*2048*2);   // rows 0..2175 init'd
  ushort_t* W_outT = (ushort_t*)alloc((size_t)1024*2048*2);
  ushort_t* xb     = (ushort_t*)alloc((size_t)4096*1024*2);
  ushort_t* U      = (ushort_t*)alloc((size_t)4096*4096*2);
  ushort_t* dl     = (ushort_t*)alloc((size_t)4096*2048*2);
  float*    Bm     = (float*)alloc((size_t)4096*16*4);
  float*    Cm     = (float*)alloc((size_t)4096*16*4);
  float*    qbuf   = (float*)alloc((size_t)NC*4096*16*4);
  float*    Sbuf   = (float*)alloc((size_t)NC*4096*4);
  float*    hin    = (float*)alloc((size_t)NC*4096*16*4);
  ushort_t* Y      = (ushort_t*)alloc((size_t)4096*2048*2);

  // 1) fused prep (incl. zero-fill of W_bigT pad rows 2080..2175)
  k_prep<<<dim3(14560),256,0,stream>>>(W_in, W_delta, W_out, W_B, W_C, x,
                                       W_inT, W_bigT, W_outT, xb);

  // 2) GEMM1: U = silu(x @ W_in) — 256x256 2-buf, 512 thr, grid 256 (1/CU)
  k_gemm2p<256,256,512,2,4,1,2><<<dim3(16,16),512,0,stream>>>(
      xb, 1024, W_inT, 1024, U, 4096, nullptr, nullptr, nullptr, 1024);

  // 3) GEMM2: dl = softplus(u@W_delta+b), fused Bm/Cm — 128x64, R17: 512 thr
  //    (8 waves x 32x32), 3 blk/CU -> 24 waves/CU; grid 1056 % 8 == 0
  k_gemm2p<128,64,512,4,2,2,6><<<dim3(33,32),512,0,stream>>>(
      U, 4096, W_bigT, 2048, dl, 2048, b_delta, Bm, Cm, 2048);

  // 4-6) chunked selective scan (NC=64 x TC=32; geometric-exp fast path)
  k_scan1<<<dim3(16,NC),256,0,stream>>>(dl, U, Bm, A_log, qbuf, Sbuf);
  k_scan_combine<<<dim3(256),256,0,stream>>>(qbuf, Sbuf, A_log, hin);
  k_scan2<<<dim3(16,NC),256,0,stream>>>(dl, U, Bm, Cm, A_log, D_par, hin, Y);

  // 7) GEMM3: out = Y @ W_out (fp32) — 128x64, R17: 512 thr, grid 512
  k_gemm2p<128,64,512,4,2,0,6><<<dim3(16,32),512,0,stream>>>(
      Y, 2048, W_outT, 2048, d_out, 1024, nullptr, nullptr, nullptr, 2048);
}